// Round 4
// baseline (4900.029 us; speedup 1.0000x reference)
//
#include <hip/hip_runtime.h>
#include <hip/hip_bf16.h>

// Problem constants (from reference)
#define HH 512
#define WW 512
#define NN 8192
#define FF 2
#define BB 8
#define MM (NN * FF)      // 16384 splats per batch
#define HW (HH * WW)      // 262144 pixels per batch image

// Tiling: 8-row strips x 64-col tiles; ONE WAVE owns one tile in registers.
#define SHLOG 3
#define SH 8                  // strip height
#define SPI (HH / SH)         // 64 strips per image
#define TPI (WW / 64)         // 8 col-tiles per strip
#define LPB (SPI * TPI)       // 512 tiles (bins) per batch
#define TILES (BB * LPB)      // 4096 tiles total
#define NBLK 128              // count/fill blocks (1024 thr, exact cover, 1 batch each)
#define BPB 16                // count-blocks per batch
#define MAXPR 12              // max (strip,coltile) pairs per record (<=6 x <=2)
#define LIST_CAP (BB * MM * MAXPR)

// ---- dual-dtype input load: f32mode ? float : bf16 ----
__device__ __forceinline__ float ld(const void* p, int i, int f32mode) {
  if (f32mode) return ((const float*)p)[i];
  unsigned u = ((const unsigned short*)p)[i];
  return __uint_as_float(u << 16);
}

__device__ __forceinline__ float readlane_f(float v, int l) {
  return __uint_as_float(__builtin_amdgcn_readlane(__float_as_uint(v), l));
}

// Abramowitz & Stegun 7.1.26, |err| <= 1.5e-7. Saturates cleanly for |x|>~5
// (expf underflow -> +-1), so out-of-window lanes self-mask via erf-diff ~ 0.
__device__ __forceinline__ float erf_f(float x) {
  float ax = fabsf(x);
  float t = 1.0f / (1.0f + 0.3275911f * ax);
  float y = t * (0.254829592f +
           t * (-0.284496736f +
           t * (1.421413741f +
           t * (-1.453152027f +
           t * 1.061405429f))));
  y = 1.0f - y * __expf(-ax * ax);
  return copysignf(y, x);
}

// (strip, col-tile) ranges touched by a record: gaussian 5s window unioned
// with the bubble's clamped bilinear footprint (f=0 records only).
__device__ __forceinline__ void tile_range(float row, float col, float s, int has_b,
                                           int& slo, int& shi, int& ctlo, int& cthi) {
  float Rf = 5.0f * s + 0.5f;
  int rlo = max(0, (int)ceilf(row - Rf)), rhi = min(HH - 1, (int)floorf(row + Rf));
  int clo = max(0, (int)ceilf(col - Rf)), chi = min(WW - 1, (int)floorf(col + Rf));
  bool empty = (rlo > rhi) || (clo > chi);
  slo = rlo >> SHLOG; shi = rhi >> SHLOG;
  ctlo = clo >> 6;    cthi = chi >> 6;
  if (has_b) {
    int r0 = (int)floorf(row), c0 = (int)floorf(col);
    int rr0 = min(max(r0, 0), HH - 1), rr1 = min(max(r0 + 1, 0), HH - 1);
    int cc0 = min(max(c0, 0), WW - 1), cc1 = min(max(c0 + 1, 0), WW - 1);
    if (empty) { slo = rr0 >> SHLOG; shi = rr1 >> SHLOG;
                 ctlo = cc0 >> 6;    cthi = cc1 >> 6; empty = false; }
    else { slo = min(slo, rr0 >> SHLOG); shi = max(shi, rr1 >> SHLOG);
           ctlo = min(ctlo, cc0 >> 6);   cthi = max(cthi, cc1 >> 6); }
  }
  if (empty) { slo = 1; shi = 0; }
}

// K1: detect dtype, invert the 8 4x4 transforms (Gauss-Jordan), f32.
__global__ void k_inv(const void* __restrict__ T, float* __restrict__ invT,
                      int* __restrict__ flag) {
  int b = threadIdx.x;
  if (b >= BB) return;
  const float* Tf = (const float*)T;
  int f32mode = (fabsf(Tf[0] - 1.f) < 0.4f &&
                 fabsf(Tf[5] - 1.f) < 0.4f &&
                 fabsf(Tf[10] - 1.f) < 0.4f) ? 1 : 0;
  if (b == 0) *flag = f32mode;

  float a[4][8];
  for (int r = 0; r < 4; ++r)
    for (int c = 0; c < 4; ++c) {
      a[r][c] = ld(T, b * 16 + r * 4 + c, f32mode);
      a[r][4 + c] = (r == c) ? 1.0f : 0.0f;
    }
  for (int k = 0; k < 4; ++k) {
    int p = k; float best = fabsf(a[k][k]);
    for (int i = k + 1; i < 4; ++i) {
      float v = fabsf(a[i][k]);
      if (v > best) { best = v; p = i; }
    }
    if (p != k)
      for (int c = 0; c < 8; ++c) { float tmp = a[k][c]; a[k][c] = a[p][c]; a[p][c] = tmp; }
    float inv = 1.0f / a[k][k];
    for (int c = 0; c < 8; ++c) a[k][c] *= inv;
    for (int i = 0; i < 4; ++i) {
      if (i == k) continue;
      float f = a[i][k];
      for (int c = 0; c < 8; ++c) a[i][c] -= f * a[k][c];
    }
  }
  for (int r = 0; r < 4; ++r)
    for (int c = 0; c < 4; ++c)
      invT[b * 16 + r * 4 + c] = a[r][4 + c];
}

// K2: project records, store table, count (record, tile) pairs per block.
// Each block covers 1024 consecutive records of ONE batch -> LPB counters.
__global__ void __launch_bounds__(1024)
k_count(const void* __restrict__ centers, const void* __restrict__ scales,
        const void* __restrict__ weights, const float* __restrict__ invT,
        const int* __restrict__ flag, float4* __restrict__ table,
        int* __restrict__ blkcnt) {
  __shared__ int cnt[LPB];
  int tid = threadIdx.x;
  if (tid < LPB) cnt[tid] = 0;
  __syncthreads();

  int idx = blockIdx.x * blockDim.x + tid;   // exact cover of [0, BB*MM)
  int f32mode = *flag;
  int b = idx >> 14;           // MM = 2^14
  int m = idx & (MM - 1);
  int n = m >> 1;              // FF = 2
  const float* Tb = invT + b * 16;
  float cx = ld(centers, 3 * n, f32mode);
  float cy = ld(centers, 3 * n + 1, f32mode);
  float cz = ld(centers, 3 * n + 2, f32mode);
  float p0 = Tb[0]  * cx + Tb[1]  * cy + Tb[2]  * cz + Tb[3];
  float p1 = Tb[4]  * cx + Tb[5]  * cy + Tb[6]  * cz + Tb[7];
  float p3 = Tb[12] * cx + Tb[13] * cy + Tb[14] * cz + Tb[15];
  float inv = 1.0f / p3;
  float4 rec;
  rec.x = p0 * inv;            // row
  rec.y = p1 * inv;            // col
  rec.z = ld(scales, m, f32mode);
  rec.w = ld(weights, m, f32mode);
  table[idx] = rec;

  int slo, shi, ctlo, cthi;
  tile_range(rec.x, rec.y, rec.z, (idx & 1) == 0, slo, shi, ctlo, cthi);
  for (int s2 = slo; s2 <= shi; ++s2)
    for (int c2 = ctlo; c2 <= cthi; ++c2)
      atomicAdd(&cnt[(s2 << 3) + c2], 1);
  __syncthreads();
  if (tid < LPB) blkcnt[blockIdx.x * LPB + tid] = cnt[tid];
}

// K3: per-block counts -> absolute fill bases (in-place) + bin offsets.
// One block, 1024 threads, 4 bins per thread.
__device__ __forceinline__ int scan_bin(int* blkcnt, int bin) {
  int b = bin >> 9, li = bin & (LPB - 1);
  int a = 0;
  for (int j = 0; j < BPB; ++j) {
    int idx = (b * BPB + j) * LPB + li;
    int c = blkcnt[idx]; blkcnt[idx] = a; a += c;
  }
  return a;
}
__device__ __forceinline__ void add_base(int* blkcnt, int bin, int base) {
  int b = bin >> 9, li = bin & (LPB - 1);
  for (int j = 0; j < BPB; ++j) blkcnt[(b * BPB + j) * LPB + li] += base;
}
__global__ void __launch_bounds__(1024)
k_scan(int* __restrict__ blkcnt, int* __restrict__ binoff) {
  __shared__ int tot[1024];
  int tid = threadIdx.x;
  int bin = tid << 2;
  int t0 = scan_bin(blkcnt, bin);
  int t1 = scan_bin(blkcnt, bin + 1);
  int t2 = scan_bin(blkcnt, bin + 2);
  int t3 = scan_bin(blkcnt, bin + 3);
  int acc = t0 + t1 + t2 + t3;
  tot[tid] = acc;
  __syncthreads();
  for (int d = 1; d < 1024; d <<= 1) {
    int v = (tid >= d) ? tot[tid - d] : 0;
    __syncthreads();
    tot[tid] += v;
    __syncthreads();
  }
  int base = tot[tid] - acc;
  binoff[bin] = base;     add_base(blkcnt, bin, base);     base += t0;
  binoff[bin + 1] = base; add_base(blkcnt, bin + 1, base); base += t1;
  binoff[bin + 2] = base; add_base(blkcnt, bin + 2, base); base += t2;
  binoff[bin + 3] = base; add_base(blkcnt, bin + 3, base);
  if (tid == 1023) binoff[TILES] = tot[1023];
}

// K4: scatter record indices into per-tile lists.
__global__ void __launch_bounds__(1024)
k_fill(const float4* __restrict__ table, const int* __restrict__ blkbase,
       int* __restrict__ list) {
  __shared__ int cur[LPB];
  int tid = threadIdx.x;
  if (tid < LPB) cur[tid] = blkbase[blockIdx.x * LPB + tid];
  __syncthreads();
  int idx = blockIdx.x * blockDim.x + tid;
  float4 rec = table[idx];
  int slo, shi, ctlo, cthi;
  tile_range(rec.x, rec.y, rec.z, (idx & 1) == 0, slo, shi, ctlo, cthi);
  for (int s2 = slo; s2 <= shi; ++s2)
    for (int c2 = ctlo; c2 <= cthi; ++c2) {
      int pos = atomicAdd(&cur[(s2 << 3) + c2], 1);
      list[pos] = idx;
    }
}

// K5: ONE WAVE per 8x64 tile, 8 registers/lane accumulator (lane = column).
// No LDS, no atomics, no syncthreads. Branchless inner loop (erf self-masks
// out-of-window lanes/rows); 2-deep software pipeline on list/table/bubble.
__global__ void __launch_bounds__(256)
k_gather(const float4* __restrict__ table, const int* __restrict__ list,
         const int* __restrict__ binoff, const void* __restrict__ bwv,
         const int* __restrict__ flag, void* __restrict__ out) {
  int tile = (blockIdx.x << 2) | (threadIdx.x >> 6);
  int lane = threadIdx.x & 63;
  int b = tile >> 9;
  int li = tile & (LPB - 1);
  int strip = li >> 3, ct = li & 7;
  int row0 = strip << SHLOG, col0 = ct << 6;
  int f32mode = *flag;

  float acc[SH];
#pragma unroll
  for (int k = 0; k < SH; ++k) acc[k] = 0.f;

  float cl = (float)(col0 + lane) - 0.5f;   // this lane's column-low boundary
  float rl = (float)(row0 + lane) - 0.5f;   // lanes 0..8: row boundaries
  int clane = col0 + lane;

  int lo = binoff[tile], hi = binoff[tile + 1];
  if (lo < hi) {
    int ia = list[lo];
    int ib = (lo + 1 < hi) ? list[lo + 1] : ia;
    float4 ra = table[ia];
    float ba = ((ia & 1) == 0) ? ld(bwv, (ia & (MM - 1)) >> 1, f32mode) : 0.f;

    for (int p = lo; p < hi; ++p) {
      // ---- prefetch: list 2 ahead, table/bubble 1 ahead ----
      int ic = (p + 2 < hi) ? list[p + 2] : ib;
      float4 rb = table[ib];
      float bb = ((ib & 1) == 0) ? ld(bwv, (ib & (MM - 1)) >> 1, f32mode) : 0.f;

      // ---- gaussian contribution of record ia ----
      float row = ra.x, col = ra.y, s = ra.z, w = ra.w;
      float rs = 0.70710678118f / s;        // 1/(s*sqrt(2))
      float x = (cl - col) * rs;
      float pw = (erf_f(x + rs) - erf_f(x)) * (0.25f * w);
      float Eh = erf_f((rl - row) * rs);    // lanes 0..8 = row boundaries
      float e0 = readlane_f(Eh, 0), e1 = readlane_f(Eh, 1);
      float e2 = readlane_f(Eh, 2), e3 = readlane_f(Eh, 3);
      float e4 = readlane_f(Eh, 4), e5 = readlane_f(Eh, 5);
      float e6 = readlane_f(Eh, 6), e7 = readlane_f(Eh, 7);
      float e8 = readlane_f(Eh, 8);
      acc[0] += (e1 - e0) * pw;
      acc[1] += (e2 - e1) * pw;
      acc[2] += (e3 - e2) * pw;
      acc[3] += (e4 - e3) * pw;
      acc[4] += (e5 - e4) * pw;
      acc[5] += (e6 - e5) * pw;
      acc[6] += (e7 - e6) * pw;
      acc[7] += (e8 - e7) * pw;

      // ---- bubble point-mass (f=0; wave-uniform branch) ----
      if ((ia & 1) == 0) {
        float r0f = floorf(row), c0f = floorf(col);
        float fr = row - r0f, fc = col - c0f;
        int r0i = (int)r0f, c0i = (int)c0f;
        int rr0 = min(max(r0i, 0), HH - 1), rr1 = min(max(r0i + 1, 0), HH - 1);
        int cc0 = min(max(c0i, 0), WW - 1), cc1 = min(max(c0i + 1, 0), WW - 1);
        float pwb = ((clane == cc0) ? (1.f - fc) : 0.f) +
                    ((clane == cc1) ? fc : 0.f);
        pwb *= ba;
        int k0 = rr0 - row0, k1 = rr1 - row0;
        float f0 = 1.f - fr, f1 = fr;
#pragma unroll
        for (int k = 0; k < SH; ++k) {
          float d = ((k == k0) ? f0 : 0.f) + ((k == k1) ? f1 : 0.f);
          acc[k] += d * pwb;
        }
      }

      ia = ib; ib = ic; ra = rb; ba = bb;
    }
  }

  // ---- flush: registers -> output (lane-contiguous per row) ----
  size_t base = (size_t)b * HW + (size_t)row0 * WW + col0 + lane;
  if (f32mode) {
    float* o = (float*)out;
#pragma unroll
    for (int k = 0; k < SH; ++k) o[base + ((size_t)k << 9)] = acc[k];
  } else {
    unsigned short* o = (unsigned short*)out;
#pragma unroll
    for (int k = 0; k < SH; ++k) {
      __hip_bfloat16 h = __float2bfloat16(acc[k]);
      o[base + ((size_t)k << 9)] = *reinterpret_cast<unsigned short*>(&h);
    }
  }
}

extern "C" void kernel_launch(void* const* d_in, const int* in_sizes, int n_in,
                              void* d_out, int out_size, void* d_ws, size_t ws_size,
                              hipStream_t stream) {
  const void* T       = d_in[0];   // (B,4,4)
  const void* centers = d_in[1];   // (N,3)
  const void* scales  = d_in[2];   // (N,F)
  const void* weights = d_in[3];   // (N,F)
  const void* bubble  = d_in[4];   // (N,)

  char* ws = (char*)d_ws;
  size_t off = 0;
  float4* table = (float4*)(ws + off); off += (size_t)BB * MM * 16;       // 2 MB
  int*    list  = (int*)(ws + off);    off += (size_t)LIST_CAP * 4;       // 6 MB
  int*    blkcnt= (int*)(ws + off);    off += (size_t)NBLK * LPB * 4;     // 256 KB
  int*    binoff= (int*)(ws + off);    off += (size_t)(TILES + 1) * 4 + 12;
  off = (off + 15) & ~(size_t)15;
  float*  invT  = (float*)(ws + off);  off += (size_t)BB * 16 * 4;        // 512 B
  int*    flag  = (int*)(ws + off);

  k_inv   <<<1,         64,   0, stream>>>(T, invT, flag);
  k_count <<<NBLK,      1024, 0, stream>>>(centers, scales, weights, invT, flag, table, blkcnt);
  k_scan  <<<1,         1024, 0, stream>>>(blkcnt, binoff);
  k_fill  <<<NBLK,      1024, 0, stream>>>(table, blkcnt, list);
  k_gather<<<TILES / 4, 256,  0, stream>>>(table, list, binoff, bubble, flag, d_out);
}